// Round 7
// baseline (597.417 us; speedup 1.0000x reference)
//
#include <hip/hip_runtime.h>

// GAT encoder: N=50000 nodes, E=800000 edges, H=4 heads, C=64 dims.
//
// R7 structure — sort-free, 3 dispatches:
//   memset(acc=0, 3.2MB)
//   -> edge_kernel: per edge compute ex[h] (4 heads) and fire-and-forget
//      atomicAdd of (D,Sx,Sy)[h] into acc[dst][16] (one 64B line per node);
//      per-block ea partial sums -> part[3125]
//   -> node_kernel: reduce part -> mean(ea); add self-loop; W-epilogue from
//      the 12 factored scalars; coalesced float4 stores
//
// Why: R3 factoring reduced per-node state to 12 scalars, so the counting
// sort (hist's contended RETURNING atomic + 3-phase scan + scattered
// scatter = ~5 kernels + ~45us hidden) only existed to group edges. Atomic
// accumulation needs no grouping. Both kernels fold the att einsums to 21
// scalars inline per block (W/att are L2-hot; ~30 wave-inst).
//
// History: R1 same-address atomic 170us -> partials. R2 1-block scan 126us
// -> 3-phase. R3 gat 78us VALU-bound -> 12-scalar factoring, 16 lanes/node.
// R4 160.6us, top-5 = harness 256MiB poison (44us, fixed). R5 FAILED
// (5-way batch, replay-only divergence, unattributed -> reverted). R6 = R4 +
// 4B packed sorted: 162us, neutral -> pipeline not stream-byte-bound.

#define N_NODES 50000
#define N_EDGES 800000
#define NB (N_EDGES / 256)          // 3125 edge blocks, exact
#define NODE_BLOCKS (N_NODES / 16)  // 3125 node blocks, exact

// ---- workspace layout (bytes) ----
constexpr size_t OFF_PART = 0;        // float[3125]
constexpr size_t OFF_ACC  = 12800;    // float[50000*16], 64B-aligned -> 3.2MB

// Fold att einsums into 21 per-head scalars in LDS:
// sm[0..7]=ws(h,k) sm[8..15]=wd(h,k) sm[16..19]=we(h)
// Call with all 256 threads; ends with __syncthreads().
__device__ __forceinline__ void compute_scal(const float* __restrict__ W,
                                             const float* __restrict__ att_src,
                                             const float* __restrict__ att_dst,
                                             const float* __restrict__ W_edge,
                                             const float* __restrict__ att_edge,
                                             float* sm) {
    int t = threadIdx.x;            // 0..255 = (h*64 + c)
    int h = t >> 6, lane = t & 63;
    float w0 = W[2 * t], w1 = W[2 * t + 1];
    float as = att_src[t], ad = att_dst[t];
    float ae = att_edge[t], wE = W_edge[t];
    float v0 = as * w0, v1 = as * w1, v2 = ad * w0, v3 = ad * w1, v4 = ae * wE;
    for (int off = 32; off; off >>= 1) {
        v0 += __shfl_down(v0, off, 64);
        v1 += __shfl_down(v1, off, 64);
        v2 += __shfl_down(v2, off, 64);
        v3 += __shfl_down(v3, off, 64);
        v4 += __shfl_down(v4, off, 64);
    }
    if (lane == 0) {
        sm[2 * h]     = v0;  sm[2 * h + 1] = v1;
        sm[8 + 2 * h] = v2;  sm[9 + 2 * h] = v3;
        sm[16 + h]    = v4;
    }
    __syncthreads();
}

// One thread per edge. 12 fire-and-forget float atomics into acc[dst][16]
// (single 64B line per node). Grid exact: 3125*256 = 800000.
__global__ __launch_bounds__(256) void edge_kernel(
        const int* __restrict__ ei, const float* __restrict__ ea,
        const float2* __restrict__ x2,
        const float* __restrict__ W, const float* __restrict__ att_src,
        const float* __restrict__ att_dst, const float* __restrict__ W_edge,
        const float* __restrict__ att_edge,
        float* __restrict__ acc, float* __restrict__ part) {
    __shared__ float sm[24];
    __shared__ float red[4];
    compute_scal(W, att_src, att_dst, W_edge, att_edge, sm);

    int e = blockIdx.x * 256 + threadIdx.x;
    int src = ei[e], dst = ei[N_EDGES + e];
    float eav = ea[e];
    float2 xs = x2[src], xd = x2[dst];
    float* a = acc + dst * 16;
#pragma unroll
    for (int h = 0; h < 4; ++h) {
        float al = xs.x * sm[2 * h] + xs.y * sm[2 * h + 1]
                 + xd.x * sm[8 + 2 * h] + xd.y * sm[9 + 2 * h]
                 + eav * sm[16 + h];
        al = fmaxf(al, 0.2f * al);          // leaky_relu(0.2)
        float ex = __expf(al);
        atomicAdd(a + h,     ex);           // D[h]
        atomicAdd(a + 4 + h, ex * xs.x);    // Sx[h]
        atomicAdd(a + 8 + h, ex * xs.y);    // Sy[h]
    }

    // per-block ea partial (for mean(ea) self-loop attr)
    float v = eav;
    for (int off = 32; off; off >>= 1) v += __shfl_down(v, off, 64);
    if ((threadIdx.x & 63) == 0) red[threadIdx.x >> 6] = v;
    __syncthreads();
    if (threadIdx.x == 0) part[blockIdx.x] = red[0] + red[1] + red[2] + red[3];
}

// 16 lanes per node, 16 nodes per block, grid = 3125 (exact).
// acc load is perfectly coalesced: addr = blk*256 + t. Broadcast the 12
// scalars within each 16-lane group via shfl; add self-loop; epilogue
// lane sub writes float4 channels j = sub+16k (head k).
__global__ __launch_bounds__(256) void node_kernel(
        const float2* __restrict__ x2, const float4* __restrict__ W4,
        const float* __restrict__ W, const float* __restrict__ att_src,
        const float* __restrict__ att_dst, const float* __restrict__ W_edge,
        const float* __restrict__ att_edge,
        const float* __restrict__ acc, const float* __restrict__ part,
        const float4* __restrict__ bias4, float4* __restrict__ out4) {
    __shared__ float sm[24];
    __shared__ float redm[4];
    compute_scal(W, att_src, att_dst, W_edge, att_edge, sm);

    // mean(ea): every block reduces the 3125 partials (L2-hot)
    int t = threadIdx.x;
    float v = 0.0f;
    for (int i = t; i < NB; i += 256) v += part[i];
    for (int off = 32; off; off >>= 1) v += __shfl_down(v, off, 64);
    if ((t & 63) == 0) redm[t >> 6] = v;
    __syncthreads();
    float meanea = (redm[0] + redm[1] + redm[2] + redm[3]) * (1.0f / N_EDGES);

    int sub = t & 15;
    int node = blockIdx.x * 16 + (t >> 4);

    float mine = acc[blockIdx.x * 256 + t];   // coalesced: node*16+sub
    float D[4], Sx[4], Sy[4];
#pragma unroll
    for (int h = 0; h < 4; ++h) {
        D[h]  = __shfl(mine, h,     16);
        Sx[h] = __shfl(mine, 4 + h, 16);
        Sy[h] = __shfl(mine, 8 + h, 16);
    }

    // self loop (src = dst = node, ea = mean of original edges)
    float2 xd = x2[node];
#pragma unroll
    for (int h = 0; h < 4; ++h) {
        float al = xd.x * (sm[2 * h] + sm[8 + 2 * h])
                 + xd.y * (sm[2 * h + 1] + sm[9 + 2 * h])
                 + meanea * sm[16 + h];
        al = fmaxf(al, 0.2f * al);
        float ex = __expf(al);
        D[h] += ex; Sx[h] += ex * xd.x; Sy[h] += ex * xd.y;
    }

#pragma unroll
    for (int k = 0; k < 4; ++k) {
        int j = sub + 16 * k;
        float invD = 1.0f / D[k];
        float4 wa = W4[2 * j], wb = W4[2 * j + 1], b = bias4[j];
        float4 o;
        o.x = (wa.x * Sx[k] + wa.y * Sy[k]) * invD + b.x;
        o.y = (wa.z * Sx[k] + wa.w * Sy[k]) * invD + b.y;
        o.z = (wb.x * Sx[k] + wb.y * Sy[k]) * invD + b.z;
        o.w = (wb.z * Sx[k] + wb.w * Sy[k]) * invD + b.w;
        out4[node * 64 + j] = o;
    }
}

extern "C" void kernel_launch(void* const* d_in, const int* in_sizes, int n_in,
                              void* d_out, int out_size, void* d_ws, size_t ws_size,
                              hipStream_t stream) {
    const float* x        = (const float*)d_in[0];
    const int*   ei       = (const int*)  d_in[1];
    const float* ea       = (const float*)d_in[2];
    const float* W        = (const float*)d_in[3];
    const float* att_src  = (const float*)d_in[4];
    const float* att_dst  = (const float*)d_in[5];
    const float* W_edge   = (const float*)d_in[6];
    const float* att_edge = (const float*)d_in[7];
    const float* bias     = (const float*)d_in[8];

    char* ws = (char*)d_ws;
    float* part = (float*)(ws + OFF_PART);
    float* acc  = (float*)(ws + OFF_ACC);

    hipMemsetAsync(acc, 0, (size_t)N_NODES * 16 * sizeof(float), stream);
    edge_kernel<<<NB, 256, 0, stream>>>(ei, ea, (const float2*)x,
                                        W, att_src, att_dst, W_edge, att_edge,
                                        acc, part);
    node_kernel<<<NODE_BLOCKS, 256, 0, stream>>>(
        (const float2*)x, (const float4*)W,
        W, att_src, att_dst, W_edge, att_edge,
        acc, part, (const float4*)bias, (float4*)d_out);
}

// Round 8
// 193.272 us; speedup vs baseline: 3.0911x; 3.0911x over previous
//
#include <hip/hip_runtime.h>

// GAT encoder: N=50000 nodes, E=800000 edges, H=4 heads, C=64 dims.
//
// R8 structure — coarse-bucket partition + LDS aggregation, 6 dispatches:
//   hist    : per-block LDS 196-bin histogram of dst>>8 -> cnt[bucket][block]
//   scan1/2/3: flat exclusive scan of cnt (612500 ints, bucket-major ->
//              one flat scan gives every (bucket,block) slot base)
//   scatter : LDS returning cursors seeded from scan; write (src|eaq16,dst)
//             8B payloads grouped by bucket; per-block ea partials
//   gat     : one block per bucket (196 x 1024): LDS acc[256 nodes][12],
//             stream payloads coalesced, 12 LDS float atomics per edge,
//             then self-loop + W-epilogue (R7-validated math)
//
// R7 lesson (measured): device-scope float atomicAdd is MEMORY-SIDE on
// gfx950 (9.6M atomics -> WRITE_SIZE 300MB = 32B each, ~19G atomics/s,
// 496us). All atomics here are LDS (in-CU) or nonexistent.
// History: R1 same-address atomic 170us; R2 1-block scan 126us -> 3-phase;
// R3 12-scalar factoring (gat 78us -> hidden); R4 160.6us (top-5 = 44us
// harness ws poison, fixed cost); R5 FAILED (5-way batch, replay-only
// divergence -> reverted); R6 162us = R4 + 4B packed sorted (neutral);
// R7 597us global-atomic experiment (reverted, but validated node math).

#define N_NODES 50000
#define N_EDGES 800000
#define NBUK 196                    // ceil(50000/256) buckets of 256 nodes
#define EBLK 3125                   // edge blocks = 800000/256 (exact)
#define CNT_N (NBUK * EBLK)         // 612500
#define CNT4_N (CNT_N / 4)          // 153125 (exact)
#define SCAN_BLKS 599               // ceil(153125/256)

// ---- workspace layout (bytes) ----
constexpr size_t OFF_PART = 0;          // float[3125]
constexpr size_t OFF_BSUM = 12544;      // int[599]
constexpr size_t OFF_BOFF = 14976;      // int[599]
constexpr size_t OFF_CNT  = 17408;      // int[612500], 16B aligned
constexpr size_t OFF_SORT = 2467456;    // int2[800000] -> ends 8867456

// Per-block LDS histogram of dst buckets; no global atomics.
__global__ __launch_bounds__(256) void hist_kernel(const int* __restrict__ ei,
                                                   int* __restrict__ cnt) {
    __shared__ int hist[NBUK];
    int t = threadIdx.x;
    if (t < NBUK) hist[t] = 0;
    __syncthreads();
    int dst = ei[N_EDGES + blockIdx.x * 256 + t];
    atomicAdd(&hist[dst >> 8], 1);
    __syncthreads();
    if (t < NBUK) cnt[t * EBLK + blockIdx.x] = hist[t];
}

// Phase 1: in-place per-block exclusive scan of cnt (int4 per thread).
__global__ __launch_bounds__(256) void scan1_kernel(int4* __restrict__ cnt4,
                                                    int* __restrict__ bsum) {
    __shared__ int sm[4];
    int t = threadIdx.x, lane = t & 63, w = t >> 6;
    int gid = blockIdx.x * 256 + t;
    int4 d = make_int4(0, 0, 0, 0);
    if (gid < CNT4_N) d = cnt4[gid];
    int mysum = d.x + d.y + d.z + d.w;
    int s = mysum;
    for (int off = 1; off < 64; off <<= 1) {
        int v = __shfl_up(s, off, 64);
        if (lane >= off) s += v;
    }
    if (lane == 63) sm[w] = s;
    __syncthreads();
    int woff = 0;
    for (int i = 0; i < 4; ++i) if (i < w) woff += sm[i];
    int base = woff + s - mysum;
    if (gid < CNT4_N) {
        int4 r;
        r.x = base;
        r.y = r.x + d.x;
        r.z = r.y + d.y;
        r.w = r.z + d.z;
        cnt4[gid] = r;
    }
    if (t == 0) bsum[blockIdx.x] = sm[0] + sm[1] + sm[2] + sm[3];
}

// Phase 2: one wave scans the 599 block sums (10 chunks of 64 with carry).
__global__ __launch_bounds__(64) void scan2_kernel(const int* __restrict__ bsum,
                                                   int* __restrict__ boff) {
    int lane = threadIdx.x;
    int carry = 0;
    for (int it = 0; it < 10; ++it) {
        int i = it * 64 + lane;
        int v = (i < SCAN_BLKS) ? bsum[i] : 0;
        int s = v;
        for (int off = 1; off < 64; off <<= 1) {
            int x = __shfl_up(s, off, 64);
            if (lane >= off) s += x;
        }
        if (i < SCAN_BLKS) boff[i] = carry + s - v;
        carry += __shfl(s, 63, 64);
    }
}

// Phase 3: add block offsets in place.
__global__ __launch_bounds__(256) void scan3_kernel(const int* __restrict__ boff,
                                                    int4* __restrict__ cnt4) {
    int gid = blockIdx.x * 256 + threadIdx.x;
    if (gid >= CNT4_N) return;
    int o = boff[blockIdx.x];
    int4 r = cnt4[gid];
    r.x += o; r.y += o; r.z += o; r.w += o;
    cnt4[gid] = r;
}

// Bucket scatter: LDS returning cursors (block's disjoint sub-ranges come
// from the scan). Also per-block ea partial sums for mean(ea).
__global__ __launch_bounds__(256) void scatter_kernel(const int* __restrict__ ei,
                                                      const float* __restrict__ ea,
                                                      const int* __restrict__ scn,
                                                      int2* __restrict__ sorted,
                                                      float* __restrict__ part) {
    __shared__ int cur[NBUK];
    __shared__ float red[4];
    int t = threadIdx.x;
    if (t < NBUK) cur[t] = scn[t * EBLK + blockIdx.x];
    __syncthreads();
    int e = blockIdx.x * 256 + t;
    int src = ei[e], dst = ei[N_EDGES + e];
    float eav = ea[e];
    unsigned eaq = (unsigned)(eav * 65535.0f + 0.5f);
    int pos = atomicAdd(&cur[dst >> 8], 1);
    sorted[pos] = make_int2(src | (int)(eaq << 16), dst);

    float v = eav;
    for (int off = 32; off; off >>= 1) v += __shfl_down(v, off, 64);
    if ((t & 63) == 0) red[t >> 6] = v;
    __syncthreads();
    if (t == 0) part[blockIdx.x] = red[0] + red[1] + red[2] + red[3];
}

// One block per bucket (196 x 1024). LDS acc[256 nodes][12] accumulates
// (D,Sx,Sy) x 4 heads via ds_add_f32; epilogue = R7-validated node math.
__global__ __launch_bounds__(1024) void gat_kernel(
        const float2* __restrict__ x2, const float4* __restrict__ W4,
        const float* __restrict__ W, const float* __restrict__ att_src,
        const float* __restrict__ att_dst, const float* __restrict__ W_edge,
        const float* __restrict__ att_edge,
        const int* __restrict__ scn, const int2* __restrict__ sorted,
        const float* __restrict__ part,
        const float4* __restrict__ bias4, float4* __restrict__ out4) {
    __shared__ float sm[24];
    __shared__ float acc[256 * 12];
    __shared__ float redm[16];
    __shared__ float smean;
    int t = threadIdx.x;
    int b = blockIdx.x;

    // fold att einsums to 20 scalars (threads 0..255 = waves 0..3)
    if (t < 256) {
        int h = t >> 6, lane = t & 63;
        float w0 = W[2 * t], w1 = W[2 * t + 1];
        float as = att_src[t], ad = att_dst[t];
        float ae = att_edge[t], wE = W_edge[t];
        float v0 = as * w0, v1 = as * w1, v2 = ad * w0, v3 = ad * w1, v4 = ae * wE;
        for (int off = 32; off; off >>= 1) {
            v0 += __shfl_down(v0, off, 64);
            v1 += __shfl_down(v1, off, 64);
            v2 += __shfl_down(v2, off, 64);
            v3 += __shfl_down(v3, off, 64);
            v4 += __shfl_down(v4, off, 64);
        }
        if (lane == 0) {
            sm[2 * h]     = v0;  sm[2 * h + 1] = v1;
            sm[8 + 2 * h] = v2;  sm[9 + 2 * h] = v3;
            sm[16 + h]    = v4;
        }
    }
    // zero acc (3072 floats / 1024 threads = 3 each)
    acc[t] = 0.0f; acc[t + 1024] = 0.0f; acc[t + 2048] = 0.0f;
    // mean(ea): reduce the 3125 partials (L2-hot)
    float v = 0.0f;
    for (int i = t; i < EBLK; i += 1024) v += part[i];
    for (int off = 32; off; off >>= 1) v += __shfl_down(v, off, 64);
    if ((t & 63) == 0) redm[t >> 6] = v;
    __syncthreads();
    if (t == 0) {
        float s = 0.0f;
        for (int i = 0; i < 16; ++i) s += redm[i];
        smean = s * (1.0f / N_EDGES);
    }
    __syncthreads();
    float meanea = smean;
    float ws0[4], ws1[4], wd0[4], wd1[4], we[4];
#pragma unroll
    for (int h = 0; h < 4; ++h) {
        ws0[h] = sm[2 * h];     ws1[h] = sm[2 * h + 1];
        wd0[h] = sm[8 + 2 * h]; wd1[h] = sm[9 + 2 * h];
        we[h]  = sm[16 + h];
    }

    int start = scn[b * EBLK];
    int end = (b < NBUK - 1) ? scn[(b + 1) * EBLK] : N_EDGES;
    for (int i = start + t; i < end; i += 1024) {
        int2 p = sorted[i];
        int src = p.x & 0xffff;
        float eav = (float)((unsigned)p.x >> 16) * (1.0f / 65535.0f);
        int dst = p.y;
        int nlo = dst & 255;
        float2 xs = x2[src], xd = x2[dst];
        float* a = &acc[nlo * 12];
#pragma unroll
        for (int h = 0; h < 4; ++h) {
            float al = xs.x * ws0[h] + xs.y * ws1[h]
                     + xd.x * wd0[h] + xd.y * wd1[h] + eav * we[h];
            al = fmaxf(al, 0.2f * al);          // leaky_relu(0.2)
            float ex = __expf(al);
            unsafeAtomicAdd(a + h,     ex);         // D[h]   (ds_add_f32)
            unsafeAtomicAdd(a + 4 + h, ex * xs.x);  // Sx[h]
            unsafeAtomicAdd(a + 8 + h, ex * xs.y);  // Sy[h]
        }
    }
    __syncthreads();

    // epilogue: 4 rounds x 64 nodes, 16 lanes per node
    int grp = t >> 4, sub = t & 15;
    for (int k = 0; k < 4; ++k) {
        int nlo = k * 64 + grp;
        int node = b * 256 + nlo;
        if (node >= N_NODES) continue;      // uniform per 16-lane group
        float val = (sub < 12) ? acc[nlo * 12 + sub] : 0.0f;
        float D[4], Sx[4], Sy[4];
#pragma unroll
        for (int h = 0; h < 4; ++h) {
            D[h]  = __shfl(val, h,     16);
            Sx[h] = __shfl(val, 4 + h, 16);
            Sy[h] = __shfl(val, 8 + h, 16);
        }
        float2 xd = x2[node];
#pragma unroll
        for (int h = 0; h < 4; ++h) {       // self loop (src=dst, ea=mean)
            float al = xd.x * (ws0[h] + wd0[h]) + xd.y * (ws1[h] + wd1[h])
                     + meanea * we[h];
            al = fmaxf(al, 0.2f * al);
            float ex = __expf(al);
            D[h] += ex; Sx[h] += ex * xd.x; Sy[h] += ex * xd.y;
        }
#pragma unroll
        for (int k2 = 0; k2 < 4; ++k2) {
            int j = sub + 16 * k2;
            float invD = 1.0f / D[k2];
            float4 wa = W4[2 * j], wb = W4[2 * j + 1], bb = bias4[j];
            float4 o;
            o.x = (wa.x * Sx[k2] + wa.y * Sy[k2]) * invD + bb.x;
            o.y = (wa.z * Sx[k2] + wa.w * Sy[k2]) * invD + bb.y;
            o.z = (wb.x * Sx[k2] + wb.y * Sy[k2]) * invD + bb.z;
            o.w = (wb.z * Sx[k2] + wb.w * Sy[k2]) * invD + bb.w;
            out4[node * 64 + j] = o;
        }
    }
}

extern "C" void kernel_launch(void* const* d_in, const int* in_sizes, int n_in,
                              void* d_out, int out_size, void* d_ws, size_t ws_size,
                              hipStream_t stream) {
    const float* x        = (const float*)d_in[0];
    const int*   ei       = (const int*)  d_in[1];
    const float* ea       = (const float*)d_in[2];
    const float* W        = (const float*)d_in[3];
    const float* att_src  = (const float*)d_in[4];
    const float* att_dst  = (const float*)d_in[5];
    const float* W_edge   = (const float*)d_in[6];
    const float* att_edge = (const float*)d_in[7];
    const float* bias     = (const float*)d_in[8];

    char* ws = (char*)d_ws;
    float* part   = (float*)(ws + OFF_PART);
    int*   bsum   = (int*)  (ws + OFF_BSUM);
    int*   boff   = (int*)  (ws + OFF_BOFF);
    int*   cnt    = (int*)  (ws + OFF_CNT);
    int2*  sorted = (int2*) (ws + OFF_SORT);

    hist_kernel<<<EBLK, 256, 0, stream>>>(ei, cnt);
    scan1_kernel<<<SCAN_BLKS, 256, 0, stream>>>((int4*)cnt, bsum);
    scan2_kernel<<<1, 64, 0, stream>>>(bsum, boff);
    scan3_kernel<<<SCAN_BLKS, 256, 0, stream>>>(boff, (int4*)cnt);
    scatter_kernel<<<EBLK, 256, 0, stream>>>(ei, ea, cnt, sorted, part);
    gat_kernel<<<NBUK, 1024, 0, stream>>>(
        (const float2*)x, (const float4*)W,
        W, att_src, att_dst, W_edge, att_edge,
        cnt, sorted, part, (const float4*)bias, (float4*)d_out);
}